// Round 14
// baseline (56.471 us; speedup 1.0000x reference)
//
#include <hip/hip_runtime.h>

#define NUM_CLASSES 80
#define CQ 20           // cls channels per quarter
#define R1 8            // REG_MAX + 1
#define HW 4096         // H*W
#define BLOCK 512       // 4 quarters x 128 threads
#define APB 512         // anchors per block (128 groups x 4 anchors)

// fast hardware transcendentals (outputs are sums of 262K O(1) terms,
// absmax threshold 122.88 -- 2-ulp native math is noise)
__device__ __forceinline__ float fexp(float x) { return __expf(x); }
__device__ __forceinline__ float flog(float x) { return __logf(x); }
__device__ __forceinline__ float frcp(float x) { return __builtin_amdgcn_rcpf(x); }

// NCH channel-strided float4 loads (16 B/lane = 1 KB/wave-load).
template<int C0, int NCH>
__device__ __forceinline__ void ldn(float4 (&d)[NCH], const float* __restrict__ u,
                                    uint32_t e) {
    #pragma unroll
    for (int j = 0; j < NCH; ++j)
        d[j] = *reinterpret_cast<const float4*>(u + (uint32_t)((C0 + j) * HW) + e);
}

__device__ __forceinline__ void cls1(float x, float& xm, float& ns) {
    xm = fmaxf(xm, x);
    float e  = fexp(-x);            // exp(-x)
    float s  = frcp(1.0f + e);      // sigmoid
    float sp = x - flog(s);         // softplus(x)
    ns = fmaf(sp * s, s, ns);
}

// 5 channels x 4 anchors; all indices compile-time
__device__ __forceinline__ void cls5x4(const float4 (&d)[5],
                                       float (&xm)[4], float (&ns)[4]) {
    #pragma unroll
    for (int j = 0; j < 5; ++j) {
        cls1(d[j].x, xm[0], ns[0]);
        cls1(d[j].y, xm[1], ns[1]);
        cls1(d[j].z, xm[2], ns[2]);
        cls1(d[j].w, xm[3], ns[3]);
    }
}

// one bbox side for one anchor from two 4-channel chunks
__device__ __forceinline__ void box8(const float (&xa)[4], const float (&xb)[4],
                                     float dk, float& corner, float& dsum) {
    float xk[8] = {xa[0], xa[1], xa[2], xa[3], xb[0], xb[1], xb[2], xb[3]};
    float m = -INFINITY;
    #pragma unroll
    for (int j = 0; j < 8; ++j) m = fmaxf(m, xk[j]);
    float se = 0.0f, swe = 0.0f;
    #pragma unroll
    for (int j = 0; j < 8; ++j) {
        float e = fexp(xk[j] - m);
        se += e;
        swe = fmaf(e, (float)j, swe);
    }
    corner = swe * frcp(se);
    const float lse = m + flog(se);     // logsumexp

    // DFL: runtime bin -> unrolled compare-select (no scratch)
    float d = fminf(fmaxf(dk, 0.0f), (float)(R1 - 1) - 0.1f);
    int tl = (int)d;                    // d >= 0: floor == trunc
    int tr = tl + 1; if (tr > R1 - 1) tr = R1 - 1;
    float x_tl = xk[0], x_tr = xk[0];
    #pragma unroll
    for (int j = 1; j < 8; ++j) {
        if (j == tl) x_tl = xk[j];
        if (j == tr) x_tr = xk[j];
    }
    dsum += (lse - x_tl) * ((float)(tl + 1) - d) + (lse - x_tr) * (d - (float)tl);
}

__global__ __launch_bounds__(BLOCK)
__attribute__((amdgpu_waves_per_eu(2, 4)))   // min=2 -> 256-VGPR allocator budget
                                             // (proven unpinned); max=4 lifts the
                                             // runtime residency cap that (2,2)
                                             // silently imposed on R7-R13
void nanodet_loss_kernel(
    const float* __restrict__ anchors,       // [N,4]
    const float* __restrict__ cls_score,     // [B,C,H,W]
    const float* __restrict__ bbox_pred,     // [B,4*R1,H,W]
    const float* __restrict__ label_weights, // [N]
    const float* __restrict__ bbox_targets,  // [N,4]
    const int*   __restrict__ labels,        // [N]
    const int*   __restrict__ nts_p,         // [1]
    const int*   __restrict__ stride_p,      // [1]
    float* __restrict__ out)
{
    const int tib = threadIdx.x;
    const int q   = tib >> 7;                // quarter: cls [20q,20q+20), side q
    const int g   = tib & 127;               // anchor group in block
    const int blk = blockIdx.x;
    const int b   = blk >> 3;                // image (uniform per block)
    const int hw0 = (blk & 7) * APB;         // window start (uniform)
    const int e   = 4 * g;                   // element offset in window
    const int n0  = blk * APB + e;           // first of this thread's 4 anchors

    const float inv_str = frcp((float)stride_p[0]);
    const float inv_nts = frcp((float)nts_p[0]);

    // quarter-uniform bases (SGPR) + per-thread element offset
    const float* cls_q = cls_score + (size_t)b * NUM_CLASSES * HW
                                   + (size_t)(q * CQ) * HW + hw0;
    const float* box_q = bbox_pred + (size_t)b * (4 * R1) * HW
                                   + (size_t)(q * R1) * HW + hw0;
    const uint32_t ue = (uint32_t)e;

    // ---- early scalar loads ----
    const int4 lab4 = *(const int4*)(labels + n0);
    int labv[4] = {lab4.x, lab4.y, lab4.z, lab4.w};

    // label-logit gather (this quarter's channel range, else dummy ch 0)
    float xlab[4];
    #pragma unroll
    for (int i = 0; i < 4; ++i) {
        const int lc = labv[i];
        const bool own = (lc >= q * CQ) && (lc < (q + 1) * CQ) && (lc < NUM_CLASSES);
        const int ch = own ? (lc - q * CQ) : 0;
        xlab[i] = cls_q[(uint32_t)ch * HW + ue + i];
    }

    // ---- cls pipeline: 4 phases x 5 channels, 2 buffers ----
    float4 A[5], B[5];
    float xm[4] = {-INFINITY, -INFINITY, -INFINITY, -INFINITY};
    float ns[4] = {0.0f, 0.0f, 0.0f, 0.0f};

    ldn<0, 5>(A, cls_q, ue);
    ldn<5, 5>(B, cls_q, ue);
    cls5x4(A, xm, ns);  ldn<10, 5>(A, cls_q, ue);
    cls5x4(B, xm, ns);  ldn<15, 5>(B, cls_q, ue);
    cls5x4(A, xm, ns);

    // issue this quarter's bbox side (two 4-channel chunks) + geometry loads;
    // latency hides under the last cls phase + geometry VALU
    float4 X[4], Y[4];
    ldn<0, 4>(X, box_q, ue);
    ldn<4, 4>(Y, box_q, ue);
    float4 a4[4], t4[4];
    #pragma unroll
    for (int i = 0; i < 4; ++i) {
        a4[i] = ((const float4*)anchors)[n0 + i];
        t4[i] = ((const float4*)bbox_targets)[n0 + i];
    }
    cls5x4(B, xm, ns);

    // geometry + this quarter's DFL distance
    float cx[4], cy[4], tx0[4], ty0[4], tx1[4], ty1[4], dk[4];
    #pragma unroll
    for (int i = 0; i < 4; ++i) {
        cx[i]  = 0.5f * (a4[i].x + a4[i].z) * inv_str;
        cy[i]  = 0.5f * (a4[i].y + a4[i].w) * inv_str;
        tx0[i] = t4[i].x * inv_str; ty0[i] = t4[i].y * inv_str;
        tx1[i] = t4[i].z * inv_str; ty1[i] = t4[i].w * inv_str;
        dk[i] = (q == 0) ? (cx[i] - tx0[i]) :
                (q == 1) ? (cy[i] - ty0[i]) :
                (q == 2) ? (tx1[i] - cx[i]) : (ty1[i] - cy[i]);
    }

    float cor[4], ds[4] = {0.0f, 0.0f, 0.0f, 0.0f};
    {
        float xa[4], xb[4];
        #pragma unroll
        for (int j = 0; j < 4; ++j) { xa[j] = X[j].x; xb[j] = Y[j].x; }
        box8(xa, xb, dk[0], cor[0], ds[0]);
        #pragma unroll
        for (int j = 0; j < 4; ++j) { xa[j] = X[j].y; xb[j] = Y[j].y; }
        box8(xa, xb, dk[1], cor[1], ds[1]);
        #pragma unroll
        for (int j = 0; j < 4; ++j) { xa[j] = X[j].z; xb[j] = Y[j].z; }
        box8(xa, xb, dk[2], cor[2], ds[2]);
        #pragma unroll
        for (int j = 0; j < 4; ++j) { xa[j] = X[j].w; xb[j] = Y[j].w; }
        box8(xa, xb, dk[3], cor[3], ds[3]);
    }

    // ---- 4-way merge via LDS (SoA float4) ----
    __shared__ float4 s_ns[3][128], s_xm[3][128], s_xl[3][128],
                      s_co[3][128], s_ds[3][128];
    if (q != 0) {
        s_ns[q - 1][g] = make_float4(ns[0], ns[1], ns[2], ns[3]);
        s_xm[q - 1][g] = make_float4(xm[0], xm[1], xm[2], xm[3]);
        s_xl[q - 1][g] = make_float4(xlab[0], xlab[1], xlab[2], xlab[3]);
        s_co[q - 1][g] = make_float4(cor[0], cor[1], cor[2], cor[3]);
        s_ds[q - 1][g] = make_float4(ds[0], ds[1], ds[2], ds[3]);
    }
    __syncthreads();

    float v0 = 0.0f, v1 = 0.0f, v2 = 0.0f, v3 = 0.0f;
    if (q == 0) {
        const float4 lw4 = *(const float4*)(label_weights + n0);
        const float lwv[4] = {lw4.x, lw4.y, lw4.z, lw4.w};
        const float4 nsq[3] = {s_ns[0][g], s_ns[1][g], s_ns[2][g]};
        const float4 xmq[3] = {s_xm[0][g], s_xm[1][g], s_xm[2][g]};
        const float4 xlq[3] = {s_xl[0][g], s_xl[1][g], s_xl[2][g]};
        const float4 coq[3] = {s_co[0][g], s_co[1][g], s_co[2][g]};
        const float4 dsq[3] = {s_ds[0][g], s_ds[1][g], s_ds[2][g]};

        #pragma unroll
        for (int i = 0; i < 4; ++i) {
            const float nsv[3] = {i==0?nsq[0].x:i==1?nsq[0].y:i==2?nsq[0].z:nsq[0].w,
                                  i==0?nsq[1].x:i==1?nsq[1].y:i==2?nsq[1].z:nsq[1].w,
                                  i==0?nsq[2].x:i==1?nsq[2].y:i==2?nsq[2].z:nsq[2].w};
            const float xmv[3] = {i==0?xmq[0].x:i==1?xmq[0].y:i==2?xmq[0].z:xmq[0].w,
                                  i==0?xmq[1].x:i==1?xmq[1].y:i==2?xmq[1].z:xmq[1].w,
                                  i==0?xmq[2].x:i==1?xmq[2].y:i==2?xmq[2].z:xmq[2].w};
            const float xlv[3] = {i==0?xlq[0].x:i==1?xlq[0].y:i==2?xlq[0].z:xlq[0].w,
                                  i==0?xlq[1].x:i==1?xlq[1].y:i==2?xlq[1].z:xlq[1].w,
                                  i==0?xlq[2].x:i==1?xlq[2].y:i==2?xlq[2].z:xlq[2].w};
            const float cov[3] = {i==0?coq[0].x:i==1?coq[0].y:i==2?coq[0].z:coq[0].w,
                                  i==0?coq[1].x:i==1?coq[1].y:i==2?coq[1].z:coq[1].w,
                                  i==0?coq[2].x:i==1?coq[2].y:i==2?coq[2].z:coq[2].w};
            const float dsv[3] = {i==0?dsq[0].x:i==1?dsq[0].y:i==2?dsq[0].z:dsq[0].w,
                                  i==0?dsq[1].x:i==1?dsq[1].y:i==2?dsq[1].z:dsq[1].w,
                                  i==0?dsq[2].x:i==1?dsq[2].y:i==2?dsq[2].z:dsq[2].w};

            const int lc = labv[i];
            const bool pos = (lc >= 0) && (lc < NUM_CLASSES);
            const float xmax_all = fmaxf(fmaxf(xm[i], xmv[0]), fmaxf(xmv[1], xmv[2]));
            const float ns_all   = ns[i] + nsv[0] + nsv[1] + nsv[2];
            const int lq = lc / CQ;                       // owning quarter
            const float xl_sel = (lq == 0) ? xlab[i] :
                                 (lq == 1) ? xlv[0] :
                                 (lq == 2) ? xlv[1] : xlv[2];
            const float ds_all = ds[i] + dsv[0] + dsv[1] + dsv[2];
            const float c0 = cor[i], c1 = cov[0], c2 = cov[1], c3 = cov[2];

            const float wt = pos ? frcp(1.0f + fexp(-xmax_all)) : 0.0f;

            const float px0 = cx[i] - c0, py0 = cy[i] - c1;
            const float px1 = cx[i] + c2, py1 = cy[i] + c3;

            const float ilx = fmaxf(px0, tx0[i]), ily = fmaxf(py0, ty0[i]);
            const float irx = fminf(px1, tx1[i]), iry = fminf(py1, ty1[i]);
            const float iw = fmaxf(irx - ilx, 0.0f), ih = fmaxf(iry - ily, 0.0f);
            const float overlap = iw * ih;
            const float ap = (px1 - px0) * (py1 - py0);
            const float at = (tx1[i] - tx0[i]) * (ty1[i] - ty0[i]);
            const float uni = fmaxf(ap + at - overlap, 1e-6f);
            const float iou = overlap * frcp(uni);

            const float elx = fminf(px0, tx0[i]), ely = fminf(py0, ty0[i]);
            const float erx = fmaxf(px1, tx1[i]), ery = fmaxf(py1, ty1[i]);
            const float ew = fmaxf(erx - elx, 0.0f), eh = fmaxf(ery - ely, 0.0f);
            const float earea = fmaxf(ew * eh, 1e-6f);
            const float giou = iou - (earea - uni) * frcp(earea);

            const float score = pos ? iou : 0.0f;
            float row = ns_all;
            if (pos) {
                const float ee = fexp(-xl_sel);
                const float s  = frcp(1.0f + ee);      // sigmoid(x_label)
                const float sp = xl_sel - flog(s);     // softplus(x_label)
                const float negterm = sp * s * s;
                const float sf = score - s;
                const float posl = (sp - xl_sel * score) * sf * sf;
                row = row - negterm + posl;
            }

            v0 += row * lwv[i];
            v1 += (1.0f - giou) * wt;
            v2 += ds_all * wt;
            v3 += wt;
        }
    }

    v0 *= inv_nts;
    v1 *= 2.0f;
    v2 *= 0.0625f;     // 0.25 / 4

    // ---------------- reduction ----------------
    #pragma unroll
    for (int off = 32; off > 0; off >>= 1) {
        v0 += __shfl_down(v0, off);
        v1 += __shfl_down(v1, off);
        v2 += __shfl_down(v2, off);
        v3 += __shfl_down(v3, off);
    }

    __shared__ float smr[8][4];   // [wave][channel]
    const int w    = tib >> 6;
    const int lane = tib & 63;
    if (lane == 0) {
        smr[w][0] = v0; smr[w][1] = v1;
        smr[w][2] = v2; smr[w][3] = v3;
    }
    __syncthreads();
    if (tib == 0) {
        float s0 = 0.0f, s1 = 0.0f, s2 = 0.0f, s3 = 0.0f;
        #pragma unroll
        for (int i = 0; i < 8; ++i) {
            s0 += smr[i][0]; s1 += smr[i][1];
            s2 += smr[i][2]; s3 += smr[i][3];
        }
        atomicAdd(&out[0], s0);
        atomicAdd(&out[1], s1);
        atomicAdd(&out[2], s2);
        atomicAdd(&out[3], s3);
    }
}

extern "C" void kernel_launch(void* const* d_in, const int* in_sizes, int n_in,
                              void* d_out, int out_size, void* d_ws, size_t ws_size,
                              hipStream_t stream) {
    const float* anchors       = (const float*)d_in[0];
    const float* cls_score     = (const float*)d_in[1];
    const float* bbox_pred     = (const float*)d_in[2];
    const float* label_weights = (const float*)d_in[3];
    const float* bbox_targets  = (const float*)d_in[4];
    const int*   labels        = (const int*)d_in[5];
    const int*   nts_p         = (const int*)d_in[6];
    const int*   stride_p      = (const int*)d_in[7];
    float* out = (float*)d_out;

    const int N = in_sizes[5];  // labels count = B*H*W

    hipMemsetAsync(d_out, 0, 4 * sizeof(float), stream);

    const int grid = N / APB;                 // 512 blocks -> 2 blocks/CU
    nanodet_loss_kernel<<<grid, BLOCK, 0, stream>>>(
        anchors, cls_score, bbox_pred, label_weights, bbox_targets,
        labels, nts_p, stride_p, out);
}

// Round 15
// 43.595 us; speedup vs baseline: 1.2954x; 1.2954x over previous
//
#include <hip/hip_runtime.h>

#define NUM_CLASSES 80
#define CPH 40          // cls channels per half
#define R1 8            // REG_MAX + 1
#define HW 4096         // H*W
#define BLOCK 512       // threads per block (2 halves x 256)
#define APB 1024        // anchors per block (4 per thread, float4 loads)

// fast hardware transcendentals (outputs are sums of 262K O(1) terms,
// absmax threshold 122.88 -- 2-ulp native math is noise)
__device__ __forceinline__ float fexp(float x) { return __expf(x); }
__device__ __forceinline__ float flog(float x) { return __logf(x); }
__device__ __forceinline__ float frcp(float x) { return __builtin_amdgcn_rcpf(x); }

__device__ __forceinline__ void cls1(float x, float& xm, float& ns) {
    xm = fmaxf(xm, x);
    float e  = fexp(-x);            // exp(-x)
    float s  = frcp(1.0f + e);      // sigmoid
    float sp = x - flog(s);         // softplus(x)
    ns = fmaf(sp * s, s, ns);
}

// one bbox side for one anchor: softmax-integral corner + DFL term
__device__ __forceinline__ void box8(const float (&xk)[8], float dk,
                                     float& corner, float& dsum) {
    float m = -INFINITY;
    #pragma unroll
    for (int j = 0; j < 8; ++j) m = fmaxf(m, xk[j]);
    float se = 0.0f, swe = 0.0f;
    #pragma unroll
    for (int j = 0; j < 8; ++j) {
        float e = fexp(xk[j] - m);
        se += e;
        swe = fmaf(e, (float)j, swe);
    }
    corner = swe * frcp(se);
    const float lse = m + flog(se);     // logsumexp

    // DFL: runtime bin -> unrolled compare-select (no scratch)
    float d = fminf(fmaxf(dk, 0.0f), (float)(R1 - 1) - 0.1f);
    int tl = (int)d;                    // d >= 0: floor == trunc
    int tr = tl + 1; if (tr > R1 - 1) tr = R1 - 1;
    float x_tl = xk[0], x_tr = xk[0];
    #pragma unroll
    for (int j = 1; j < 8; ++j) {
        if (j == tl) x_tl = xk[j];
        if (j == tr) x_tr = xk[j];
    }
    dsum += (lse - x_tl) * ((float)(tl + 1) - d) + (lse - x_tr) * (d - (float)tl);
}

__global__ __launch_bounds__(BLOCK)
__attribute__((amdgpu_waves_per_eu(2, 2)))   // 256-VGPR budget: the only setting
                                             // that unpins the allocator from 64
void nanodet_loss_kernel(
    const float* __restrict__ anchors,       // [N,4]
    const float* __restrict__ cls_score,     // [B,C,H,W]
    const float* __restrict__ bbox_pred,     // [B,4*R1,H,W]
    const float* __restrict__ label_weights, // [N]
    const float* __restrict__ bbox_targets,  // [N,4]
    const int*   __restrict__ labels,        // [N]
    const int*   __restrict__ nts_p,         // [1]
    const int*   __restrict__ stride_p,      // [1]
    float* __restrict__ out)
{
    const int tib = threadIdx.x;
    const int h   = tib >> 8;                // half: 0 -> cls 0-39 / sides 0,1
    const int u   = tib & 255;               //       1 -> cls 40-79 / sides 2,3
    const int blk = blockIdx.x;
    const int b   = blk >> 2;                // image (uniform per block)
    const int hw0 = (blk & 3) * APB;         // window start (uniform)
    const int e   = 4 * u;                   // element offset in window
    const int n0  = blk * APB + e;           // first of this thread's 4 anchors

    const float inv_str = frcp((float)stride_p[0]);
    const float inv_nts = frcp((float)nts_p[0]);

    // block-half-uniform bases (SGPR) + per-thread element offset
    const float* cls_h = cls_score + (size_t)b * NUM_CLASSES * HW
                                   + (size_t)(h * CPH) * HW + hw0;
    const float* box_h = bbox_pred + (size_t)b * (4 * R1) * HW
                                   + (size_t)(h * 16) * HW + hw0;
    const uint32_t ue = (uint32_t)e;

    // ---- label load + label-logit gather (oldest in queue, small) ----
    const int4 lab4 = *(const int4*)(labels + n0);
    int labv[4] = {lab4.x, lab4.y, lab4.z, lab4.w};
    float xlab[4];
    #pragma unroll
    for (int i = 0; i < 4; ++i) {
        const int lc = labv[i];
        const bool own = (h == 0) ? (lc >= 0 && lc < CPH)
                                  : (lc >= CPH && lc < NUM_CLASSES);
        const int ch = own ? (lc - h * CPH) : 0;
        xlab[i] = cls_h[(uint32_t)ch * HW + ue + i];
    }

    // ---- THE EXPERIMENT: issue ALL 40 cls channel float4 loads before any
    //      consumption (40 KB in flight per wave; ~320 KB/CU at 8 waves/CU).
    //      Straight-line code -> compiler emits incremental counted vmcnt
    //      before each consume group (m131). VGPR_Count is the validity
    //      check: ~200 = loads hoisted; ~100 = folded (experiment void). ----
    float4 X[CPH];
    #pragma unroll
    for (int j = 0; j < CPH; ++j)
        X[j] = *reinterpret_cast<const float4*>(cls_h + (uint32_t)(j * HW) + ue);

    float xm[4] = {-INFINITY, -INFINITY, -INFINITY, -INFINITY};
    float ns[4] = {0.0f, 0.0f, 0.0f, 0.0f};

    // consume first 16 channels (frees 64 VGPRs for the box loads)
    #pragma unroll
    for (int j = 0; j < 16; ++j) {
        cls1(X[j].x, xm[0], ns[0]);
        cls1(X[j].y, xm[1], ns[1]);
        cls1(X[j].z, xm[2], ns[2]);
        cls1(X[j].w, xm[3], ns[3]);
    }

    // issue this half's 16 box-channel loads
    float4 Xb[16];
    #pragma unroll
    for (int j = 0; j < 16; ++j)
        Xb[j] = *reinterpret_cast<const float4*>(box_h + (uint32_t)(j * HW) + ue);

    // issue geometry loads
    float4 a4[4], t4[4];
    #pragma unroll
    for (int i = 0; i < 4; ++i) {
        a4[i] = ((const float4*)anchors)[n0 + i];
        t4[i] = ((const float4*)bbox_targets)[n0 + i];
    }

    // consume remaining 24 cls channels
    #pragma unroll
    for (int j = 16; j < CPH; ++j) {
        cls1(X[j].x, xm[0], ns[0]);
        cls1(X[j].y, xm[1], ns[1]);
        cls1(X[j].z, xm[2], ns[2]);
        cls1(X[j].w, xm[3], ns[3]);
    }

    // geometry + this half's DFL distances
    float cx[4], cy[4], tx0[4], ty0[4], tx1[4], ty1[4], dk0[4], dk1[4];
    #pragma unroll
    for (int i = 0; i < 4; ++i) {
        cx[i]  = 0.5f * (a4[i].x + a4[i].z) * inv_str;
        cy[i]  = 0.5f * (a4[i].y + a4[i].w) * inv_str;
        tx0[i] = t4[i].x * inv_str; ty0[i] = t4[i].y * inv_str;
        tx1[i] = t4[i].z * inv_str; ty1[i] = t4[i].w * inv_str;
        dk0[i] = (h == 0) ? (cx[i] - tx0[i]) : (tx1[i] - cx[i]);
        dk1[i] = (h == 0) ? (cy[i] - ty0[i]) : (ty1[i] - cy[i]);
    }

    // box compute: side 2h from Xb[0..7], side 2h+1 from Xb[8..15]
    float corA[4], corB[4], ds[4] = {0.0f, 0.0f, 0.0f, 0.0f};
    {
        float xk[8];
        #pragma unroll
        for (int j = 0; j < 8; ++j) xk[j] = Xb[j].x;
        box8(xk, dk0[0], corA[0], ds[0]);
        #pragma unroll
        for (int j = 0; j < 8; ++j) xk[j] = Xb[j].y;
        box8(xk, dk0[1], corA[1], ds[1]);
        #pragma unroll
        for (int j = 0; j < 8; ++j) xk[j] = Xb[j].z;
        box8(xk, dk0[2], corA[2], ds[2]);
        #pragma unroll
        for (int j = 0; j < 8; ++j) xk[j] = Xb[j].w;
        box8(xk, dk0[3], corA[3], ds[3]);

        #pragma unroll
        for (int j = 0; j < 8; ++j) xk[j] = Xb[8 + j].x;
        box8(xk, dk1[0], corB[0], ds[0]);
        #pragma unroll
        for (int j = 0; j < 8; ++j) xk[j] = Xb[8 + j].y;
        box8(xk, dk1[1], corB[1], ds[1]);
        #pragma unroll
        for (int j = 0; j < 8; ++j) xk[j] = Xb[8 + j].z;
        box8(xk, dk1[2], corB[2], ds[2]);
        #pragma unroll
        for (int j = 0; j < 8; ++j) xk[j] = Xb[8 + j].w;
        box8(xk, dk1[3], corB[3], ds[3]);
    }

    // ---- cross-half merge via LDS (SoA float4: conflict-free b128) ----
    __shared__ float4 s_ns[256], s_xm[256], s_xl[256],
                      s_cA[256], s_cB[256], s_ds[256];
    if (h == 1) {
        s_ns[u] = make_float4(ns[0], ns[1], ns[2], ns[3]);
        s_xm[u] = make_float4(xm[0], xm[1], xm[2], xm[3]);
        s_xl[u] = make_float4(xlab[0], xlab[1], xlab[2], xlab[3]);
        s_cA[u] = make_float4(corA[0], corA[1], corA[2], corA[3]);
        s_cB[u] = make_float4(corB[0], corB[1], corB[2], corB[3]);
        s_ds[u] = make_float4(ds[0], ds[1], ds[2], ds[3]);
    }
    __syncthreads();

    float v0 = 0.0f, v1 = 0.0f, v2 = 0.0f, v3 = 0.0f;
    if (h == 0) {
        const float4 lw4 = *(const float4*)(label_weights + n0);
        const float lwv[4] = {lw4.x, lw4.y, lw4.z, lw4.w};
        const float4 q_ns = s_ns[u], q_xm = s_xm[u], q_xl = s_xl[u],
                     q_cA = s_cA[u], q_cB = s_cB[u], q_ds = s_ds[u];
        const float ns1[4] = {q_ns.x, q_ns.y, q_ns.z, q_ns.w};
        const float xm1[4] = {q_xm.x, q_xm.y, q_xm.z, q_xm.w};
        const float xl1[4] = {q_xl.x, q_xl.y, q_xl.z, q_xl.w};
        const float c2a[4] = {q_cA.x, q_cA.y, q_cA.z, q_cA.w};
        const float c3a[4] = {q_cB.x, q_cB.y, q_cB.z, q_cB.w};
        const float ds1[4] = {q_ds.x, q_ds.y, q_ds.z, q_ds.w};

        #pragma unroll
        for (int i = 0; i < 4; ++i) {
            const int lc = labv[i];
            const bool pos = (lc >= 0) && (lc < NUM_CLASSES);
            const float xmax_all = fmaxf(xm[i], xm1[i]);
            const float ns_all   = ns[i] + ns1[i];
            const float xl_sel   = (lc < CPH) ? xlab[i] : xl1[i];
            const float ds_all   = ds[i] + ds1[i];

            const float wt = pos ? frcp(1.0f + fexp(-xmax_all)) : 0.0f;

            const float px0 = cx[i] - corA[i], py0 = cy[i] - corB[i];
            const float px1 = cx[i] + c2a[i],  py1 = cy[i] + c3a[i];

            const float ilx = fmaxf(px0, tx0[i]), ily = fmaxf(py0, ty0[i]);
            const float irx = fminf(px1, tx1[i]), iry = fminf(py1, ty1[i]);
            const float iw = fmaxf(irx - ilx, 0.0f), ih = fmaxf(iry - ily, 0.0f);
            const float overlap = iw * ih;
            const float ap = (px1 - px0) * (py1 - py0);
            const float at = (tx1[i] - tx0[i]) * (ty1[i] - ty0[i]);
            const float uni = fmaxf(ap + at - overlap, 1e-6f);
            const float iou = overlap * frcp(uni);

            const float elx = fminf(px0, tx0[i]), ely = fminf(py0, ty0[i]);
            const float erx = fmaxf(px1, tx1[i]), ery = fmaxf(py1, ty1[i]);
            const float ew = fmaxf(erx - elx, 0.0f), eh = fmaxf(ery - ely, 0.0f);
            const float earea = fmaxf(ew * eh, 1e-6f);
            const float giou = iou - (earea - uni) * frcp(earea);

            const float score = pos ? iou : 0.0f;
            float row = ns_all;
            if (pos) {
                const float ee = fexp(-xl_sel);
                const float s  = frcp(1.0f + ee);      // sigmoid(x_label)
                const float sp = xl_sel - flog(s);     // softplus(x_label)
                const float negterm = sp * s * s;
                const float sf = score - s;
                const float posl = (sp - xl_sel * score) * sf * sf;
                row = row - negterm + posl;
            }

            v0 += row * lwv[i];
            v1 += (1.0f - giou) * wt;
            v2 += ds_all * wt;
            v3 += wt;
        }
    }

    v0 *= inv_nts;
    v1 *= 2.0f;
    v2 *= 0.0625f;     // 0.25 / 4

    // ---------------- reduction ----------------
    #pragma unroll
    for (int off = 32; off > 0; off >>= 1) {
        v0 += __shfl_down(v0, off);
        v1 += __shfl_down(v1, off);
        v2 += __shfl_down(v2, off);
        v3 += __shfl_down(v3, off);
    }

    __shared__ float smr[8][4];   // [wave][channel]
    const int w    = tib >> 6;
    const int lane = tib & 63;
    if (lane == 0) {
        smr[w][0] = v0; smr[w][1] = v1;
        smr[w][2] = v2; smr[w][3] = v3;
    }
    __syncthreads();
    if (tib == 0) {
        float s0 = 0.0f, s1 = 0.0f, s2 = 0.0f, s3 = 0.0f;
        #pragma unroll
        for (int i = 0; i < 8; ++i) {
            s0 += smr[i][0]; s1 += smr[i][1];
            s2 += smr[i][2]; s3 += smr[i][3];
        }
        atomicAdd(&out[0], s0);
        atomicAdd(&out[1], s1);
        atomicAdd(&out[2], s2);
        atomicAdd(&out[3], s3);
    }
}

extern "C" void kernel_launch(void* const* d_in, const int* in_sizes, int n_in,
                              void* d_out, int out_size, void* d_ws, size_t ws_size,
                              hipStream_t stream) {
    const float* anchors       = (const float*)d_in[0];
    const float* cls_score     = (const float*)d_in[1];
    const float* bbox_pred     = (const float*)d_in[2];
    const float* label_weights = (const float*)d_in[3];
    const float* bbox_targets  = (const float*)d_in[4];
    const int*   labels        = (const int*)d_in[5];
    const int*   nts_p         = (const int*)d_in[6];
    const int*   stride_p      = (const int*)d_in[7];
    float* out = (float*)d_out;

    const int N = in_sizes[5];  // labels count = B*H*W

    hipMemsetAsync(d_out, 0, 4 * sizeof(float), stream);

    const int grid = N / APB;                 // 256 blocks
    nanodet_loss_kernel<<<grid, BLOCK, 0, stream>>>(
        anchors, cls_score, bbox_pred, label_weights, bbox_targets,
        labels, nts_p, stride_p, out);
}